// Round 4
// baseline (1020.222 us; speedup 1.0000x reference)
//
#include <hip/hip_runtime.h>
#include <hip/hip_bf16.h>

// Problem constants
#define N_TOK   576
#define MPAD    640            // padded to 5*128
#define DIM     1024
#define VOCAB   262400
#define BM      128
#define BN      256
#define BK      64
#define NT      (DIM/BK)       // 16 K-steps
#define RB      5              // MPAD/BM row blocks
#define VBLKS   (VOCAB/BN)     // 1025
#define NWG     (RB*VBLKS)     // 5125
#define ABUF    (BM*BK)        // 8192 elems (16 KB)
#define BBUF    (BN*BK)        // 16384 elems (32 KB)
#define IGNORE_INDEX (-100)

typedef float  f32x4  __attribute__((ext_vector_type(4)));
typedef short  bf16x8 __attribute__((ext_vector_type(8)));
typedef unsigned short u16x8 __attribute__((ext_vector_type(8)));

__device__ __forceinline__ unsigned cvt_pk_bf16(float a, float b) {
  union { __hip_bfloat162 h; unsigned u; } c;
  c.h = __float22bfloat162_rn(make_float2(a, b));   // -> v_cvt_pk_bf16_f32
  return c.u;
}

// ---------- kernel 1: x fp32 -> bf16, rows [576,640) zero-padded ----------
__global__ void k_cvt_x(const float* __restrict__ x, unsigned short* __restrict__ xb) {
  int idx = blockIdx.x * 256 + threadIdx.x;     // 81920 threads * 8 elems
  long e0 = (long)idx * 8;
  int row = (int)(e0 >> 10);
  union { u16x8 v; unsigned u[4]; } o;
  if (row < N_TOK) {
    const float4 f0 = *(const float4*)(x + e0);
    const float4 f1 = *(const float4*)(x + e0 + 4);
    o.u[0] = cvt_pk_bf16(f0.x, f0.y);
    o.u[1] = cvt_pk_bf16(f0.z, f0.w);
    o.u[2] = cvt_pk_bf16(f1.x, f1.y);
    o.u[3] = cvt_pk_bf16(f1.z, f1.w);
  } else {
    o.u[0] = o.u[1] = o.u[2] = o.u[3] = 0u;
  }
  *(u16x8*)(xb + e0) = o.v;
}

// ---------- kernel 2: main GEMM + softcap + exp + row-sum ----------
// Counted-vmcnt pipeline, 3-buffer LDS rotation, ONE raw s_barrier per K-step.
// Iter t: read buf[t%3] -> MFMA; issue stage of t+2 (B->regs, A->LDS t+2 buf);
// cvt+ds_write B(t+1); lgkmcnt(0); vmcnt(10) [leaves t+2's 10-op group in
// flight ACROSS the barrier]; s_barrier. 3 buffers => write target is never
// the currently-read buffer; publish of tile t+1 is exactly the barrier.
// LDS swizzle: 16B chunk j of row r at slot (j ^ (r&7)) -> conflict-free.
__global__ __launch_bounds__(512, 2) void k_gemm(
    const float* __restrict__ W,            // [VOCAB][DIM] fp32
    const unsigned short* __restrict__ Xb,  // [MPAD][DIM] bf16
    float* __restrict__ S)                  // [MPAD] running sum of exp(z-30)
{
  __shared__ unsigned short As[3 * ABUF];   // 48 KB, swizzled
  __shared__ unsigned short Bs[3 * BBUF];   // 96 KB, swizzled

  // ---- bijective XCD swizzle (m204), rb-fastest logical order ----
  const int q  = NWG / 8, rm = NWG % 8;     // 640, 5
  const int orig = blockIdx.x;
  const int xcd  = orig & 7;
  const int part = orig >> 3;
  const int bid  = (xcd < rm ? xcd * (q + 1) : rm * (q + 1) + (xcd - rm) * q) + part;

  const int rb  = bid % RB;
  const int vb  = bid / RB;
  const int m0  = rb * BM;
  const long n0 = (long)vb * BN;

  const int t   = threadIdx.x;
  const int l   = t & 63;
  const int w   = t >> 6;                   // 0..7
  const int wm  = w >> 2, wn = w & 3;       // 2x4 wave grid, 64x64 per wave
  const int l15 = l & 15, lh = l >> 4;
  const int e8  = l15 & 7;

  // per-thread staging geometry
  int aR[2], aKB[2];                        // A: 2 x 16B chunks/thread
  #pragma unroll
  for (int i = 0; i < 2; ++i) {
    int lin = t + i * 512;                  // 0..1023
    aR[i]  = lin >> 3;
    aKB[i] = (lin & 7) ^ (aR[i] & 7);       // pre-swizzled source chunk
  }
  int bR[4], bJ[4], bC[4];                  // B: 4 x 16B chunks/thread
  #pragma unroll
  for (int i = 0; i < 4; ++i) {
    int lin = t + i * 512;                  // 0..2047
    bR[i] = lin >> 3;                       // row 0..255
    bJ[i] = lin & 7;
    bC[i] = bJ[i] ^ (bR[i] & 7);            // swizzled LDS chunk
  }

  f32x4 acc[4][4];
  const f32x4 zero4 = {0.0f, 0.0f, 0.0f, 0.0f};
  #pragma unroll
  for (int i = 0; i < 4; ++i)
    #pragma unroll
    for (int j = 0; j < 4; ++j) acc[i][j] = zero4;

#define ISSUE_B(FB, K0N)                                                     \
  _Pragma("unroll")                                                          \
  for (int i = 0; i < 4; ++i) {                                              \
    const float* g = W + (n0 + bR[i]) * DIM + (K0N) + bJ[i] * 8;             \
    FB[i][0] = *(const float4*)g;                                            \
    FB[i][1] = *(const float4*)(g + 4);                                      \
  }

#define ISSUE_A(BUFI, K0N)                                                   \
  _Pragma("unroll")                                                          \
  for (int i = 0; i < 2; ++i) {                                              \
    int lin = t + i * 512;                                                   \
    const unsigned short* g = Xb + (size_t)(m0 + aR[i]) * DIM + (K0N) + aKB[i] * 8; \
    __builtin_amdgcn_global_load_lds(                                        \
        (const __attribute__((address_space(1))) void*)g,                    \
        (__attribute__((address_space(3))) void*)(As + (BUFI) * ABUF + (size_t)lin * 8), \
        16, 0, 0);                                                           \
  }

#define WRITE_B(FB, BUFI)                                                    \
  _Pragma("unroll")                                                          \
  for (int i = 0; i < 4; ++i) {                                              \
    union { u16x8 v; unsigned u[4]; } o;                                     \
    o.u[0] = cvt_pk_bf16(FB[i][0].x, FB[i][0].y);                            \
    o.u[1] = cvt_pk_bf16(FB[i][0].z, FB[i][0].w);                            \
    o.u[2] = cvt_pk_bf16(FB[i][1].x, FB[i][1].y);                            \
    o.u[3] = cvt_pk_bf16(FB[i][1].z, FB[i][1].w);                            \
    *(u16x8*)(Bs + (BUFI) * BBUF + bR[i] * BK + bC[i] * 8) = o.v;            \
  }

#define COMPUTE(BUFI)                                                        \
  {                                                                          \
    bf16x8 af[4][2], bfr[4][2];                                              \
    _Pragma("unroll")                                                        \
    for (int mi = 0; mi < 4; ++mi)                                           \
      _Pragma("unroll")                                                      \
      for (int kk = 0; kk < 2; ++kk)                                         \
        af[mi][kk] = *(const bf16x8*)(As + (BUFI) * ABUF                     \
            + (wm*64 + mi*16 + l15) * BK + (((kk*4 + lh) ^ e8) * 8));        \
    _Pragma("unroll")                                                        \
    for (int ni = 0; ni < 4; ++ni)                                           \
      _Pragma("unroll")                                                      \
      for (int kk = 0; kk < 2; ++kk)                                         \
        bfr[ni][kk] = *(const bf16x8*)(Bs + (BUFI) * BBUF                    \
            + (wn*64 + ni*16 + l15) * BK + (((kk*4 + lh) ^ e8) * 8));        \
    __builtin_amdgcn_s_setprio(1);                                           \
    _Pragma("unroll")                                                        \
    for (int kk = 0; kk < 2; ++kk)                                           \
      _Pragma("unroll")                                                      \
      for (int mi = 0; mi < 4; ++mi)                                         \
        _Pragma("unroll")                                                    \
        for (int ni = 0; ni < 4; ++ni)                                       \
          acc[mi][ni] = __builtin_amdgcn_mfma_f32_16x16x32_bf16(             \
              af[mi][kk], bfr[ni][kk], acc[mi][ni], 0, 0, 0);                \
    __builtin_amdgcn_s_setprio(0);                                           \
  }

  float4 fbA[4][2], fbB[4][2];              // named reg dbuf (rule #20)

  // ---- prologue: stage tiles 0 (buf0) and 1 (buf1) ----
  ISSUE_B(fbA, 0);                          // queue: B0 x8
  ISSUE_A(0, 0);                            // + A0 x2
  ISSUE_B(fbB, BK);                         // + B1 x8
  ISSUE_A(1, BK);                           // + A1 x2   (20 outstanding)
  WRITE_B(fbA, 0);                          // compiler waits fbA (drains B0)
  asm volatile("s_waitcnt lgkmcnt(0)" ::: "memory");
  asm volatile("s_waitcnt vmcnt(10)" ::: "memory");   // A0 landed; B1+A1 in flight
  __builtin_amdgcn_s_barrier();

  int cur = 0;
  for (int kt = 0; kt < NT; kt += 2) {
    const int c1 = (cur + 1 < 3) ? cur + 1 : 0;
    const int c2 = (c1 + 1 < 3) ? c1 + 1 : 0;

    // ---- even step: compute tile kt, stage kt+2, write B(kt+1) ----
    COMPUTE(cur);
    if (kt + 2 < NT) {
      ISSUE_B(fbA, (kt + 2) * BK);
      ISSUE_A(c2, (kt + 2) * BK);
    }
    __builtin_amdgcn_sched_barrier(0);      // keep cvt's vmcnt wait late
    WRITE_B(fbB, c1);
    asm volatile("s_waitcnt lgkmcnt(0)" ::: "memory");
    if (kt + 2 < NT) asm volatile("s_waitcnt vmcnt(10)" ::: "memory");
    else             asm volatile("s_waitcnt vmcnt(0)"  ::: "memory");
    __builtin_amdgcn_s_barrier();

    // ---- odd step: compute tile kt+1, stage kt+3, write B(kt+2) ----
    COMPUTE(c1);
    if (kt + 3 < NT) {
      ISSUE_B(fbB, (kt + 3) * BK);
      ISSUE_A(cur, (kt + 3) * BK);          // (kt+3)%3 == kt%3 == cur
    }
    if (kt + 2 < NT) {
      __builtin_amdgcn_sched_barrier(0);
      WRITE_B(fbA, c2);
      asm volatile("s_waitcnt lgkmcnt(0)" ::: "memory");
      if (kt + 3 < NT) asm volatile("s_waitcnt vmcnt(10)" ::: "memory");
      else             asm volatile("s_waitcnt vmcnt(0)"  ::: "memory");
      __builtin_amdgcn_s_barrier();
    }
    cur = c2;
  }

  // ---- epilogue: p = exp(z-30) = exp(-60/(exp(g/15)+1)), row sums, atomics
  // C frag layout: col = l&15 (vocab), row = (l>>4)*4 + j (token)
  float red[4][4];
  #pragma unroll
  for (int mi = 0; mi < 4; ++mi) {
    #pragma unroll
    for (int j = 0; j < 4; ++j) {
      float s = 0.0f;
      #pragma unroll
      for (int ni = 0; ni < 4; ++ni) {
        float g   = acc[mi][ni][j];
        float tp1 = __expf(g * (1.0f / 15.0f)) + 1.0f;
        s += __expf(-60.0f * __builtin_amdgcn_rcpf(tp1));
      }
      s += __shfl_xor(s, 1);
      s += __shfl_xor(s, 2);
      s += __shfl_xor(s, 4);
      s += __shfl_xor(s, 8);
      red[mi][j] = s;                       // sum over this wave's 64 cols
    }
  }
  if (l15 == 0) {
    #pragma unroll
    for (int mi = 0; mi < 4; ++mi)
      #pragma unroll
      for (int j = 0; j < 4; ++j) {
        int row = m0 + wm*64 + mi*16 + lh*4 + j;
        atomicAdd(&S[row], red[mi][j]);     // padded rows land in S[576..640)
      }
  }
#undef ISSUE_B
#undef ISSUE_A
#undef WRITE_B
#undef COMPUTE
}

// ---------- kernel 3: exact fp32 target logits ----------
__global__ void k_tgt(const float* __restrict__ x, const float* __restrict__ W,
                      const int* __restrict__ labels, float* __restrict__ tgt) {
  int n = blockIdx.x;
  int lab = labels[n];
  int t = threadIdx.x;                       // 256 threads * 4 floats = 1024
  float s = 0.0f;
  if (lab >= 0) {
    const float4 a = ((const float4*)(x + (size_t)n * DIM))[t];
    const float4 b = ((const float4*)(W + (size_t)lab * DIM))[t];
    s = a.x*b.x + a.y*b.y + a.z*b.z + a.w*b.w;
  }
  #pragma unroll
  for (int off = 32; off >= 1; off >>= 1) s += __shfl_xor(s, off);
  __shared__ float wsum[4];
  if ((t & 63) == 0) wsum[t >> 6] = s;
  __syncthreads();
  if (t == 0) {
    float d = wsum[0] + wsum[1] + wsum[2] + wsum[3];
    tgt[n] = (lab >= 0) ? 30.0f * tanhf(d * (1.0f / 30.0f)) : 0.0f;
  }
}

// ---------- kernel 4: final reduce -> loss ----------
__global__ void k_final(const float* __restrict__ S, const float* __restrict__ tgt,
                        const int* __restrict__ labels, float* __restrict__ out) {
  int t = threadIdx.x;
  float sum = 0.0f, cnt = 0.0f;
  for (int n = t; n < N_TOK; n += 256) {
    if (labels[n] != IGNORE_INDEX) {
      sum += 30.0f + __logf(S[n]) - tgt[n];  // lse = 30 + log(sum exp(z-30))
      cnt += 1.0f;
    }
  }
  #pragma unroll
  for (int off = 32; off >= 1; off >>= 1) {
    sum += __shfl_xor(sum, off);
    cnt += __shfl_xor(cnt, off);
  }
  __shared__ float as_[4], ac_[4];
  if ((t & 63) == 0) { as_[t >> 6] = sum; ac_[t >> 6] = cnt; }
  __syncthreads();
  if (t == 0) {
    float ts = as_[0] + as_[1] + as_[2] + as_[3];
    float tc = ac_[0] + ac_[1] + ac_[2] + ac_[3];
    out[0] = ts / tc;
  }
}

extern "C" void kernel_launch(void* const* d_in, const int* in_sizes, int n_in,
                              void* d_out, int out_size, void* d_ws, size_t ws_size,
                              hipStream_t stream) {
  const float* x      = (const float*)d_in[0];
  const float* W      = (const float*)d_in[1];
  const int*   labels = (const int*)d_in[2];
  float* out = (float*)d_out;

  // ws layout: xb [640*1024 bf16] | S [640 f32] | tgt [576 f32]  (~1.26 MB)
  char* ws = (char*)d_ws;
  unsigned short* xb = (unsigned short*)ws;
  float* S   = (float*)(ws + (size_t)MPAD * DIM * 2);
  float* tgt = (float*)(ws + (size_t)MPAD * DIM * 2 + MPAD * 4);

  hipMemsetAsync(S, 0, MPAD * sizeof(float), stream);   // zero accumulators
  k_cvt_x<<<MPAD * DIM / (256 * 8), 256, 0, stream>>>(x, xb);
  k_gemm<<<NWG, 512, 0, stream>>>(W, xb, S);
  k_tgt<<<N_TOK, 256, 0, stream>>>(x, W, labels, tgt);
  k_final<<<1, 256, 0, stream>>>(S, tgt, labels, out);
}

// Round 5
// 797.718 us; speedup vs baseline: 1.2789x; 1.2789x over previous
//
#include <hip/hip_runtime.h>
#include <hip/hip_bf16.h>

// Problem constants
#define N_TOK   576
#define MPAD    640            // padded to 5*128
#define DIM     1024
#define VOCAB   262400
#define BM      128            // tokens per block
#define BN      256            // vocab per block (4 waves x 64)
#define RB      5              // MPAD/BM token blocks
#define VBLKS   (VOCAB/BN)     // 1025
#define NWG     (RB*VBLKS)     // 5125
#define PANE    16384          // A panel elems: 128 rows x 128 k (32KB)
#define IGNORE_INDEX (-100)

typedef float  f32x4  __attribute__((ext_vector_type(4)));
typedef short  bf16x8 __attribute__((ext_vector_type(8)));
typedef unsigned short u16x8 __attribute__((ext_vector_type(8)));

#define AS1 __attribute__((address_space(1)))
#define AS3 __attribute__((address_space(3)))

__device__ __forceinline__ unsigned cvt_pk_bf16(float a, float b) {
  union { __hip_bfloat162 h; unsigned u; } c;
  c.h = __float22bfloat162_rn(make_float2(a, b));   // -> v_cvt_pk_bf16_f32
  return c.u;
}

// ---------- kernel 1: x fp32 -> bf16, rows [576,640) zero-padded ----------
__global__ void k_cvt_x(const float* __restrict__ x, unsigned short* __restrict__ xb) {
  int idx = blockIdx.x * 256 + threadIdx.x;     // 81920 threads * 8 elems
  long e0 = (long)idx * 8;
  int row = (int)(e0 >> 10);
  union { u16x8 v; unsigned u[4]; } o;
  if (row < N_TOK) {
    const float4 f0 = *(const float4*)(x + e0);
    const float4 f1 = *(const float4*)(x + e0 + 4);
    o.u[0] = cvt_pk_bf16(f0.x, f0.y);
    o.u[1] = cvt_pk_bf16(f0.z, f0.w);
    o.u[2] = cvt_pk_bf16(f1.x, f1.y);
    o.u[3] = cvt_pk_bf16(f1.z, f1.w);
  } else {
    o.u[0] = o.u[1] = o.u[2] = o.u[3] = 0u;
  }
  *(u16x8*)(xb + e0) = o.v;
}

// ---------- kernel 2: main GEMM + softcap + exp + row-sum ----------
// B (W, fp32) is loaded DIRECTLY global->regs as MFMA fragments (8 consecutive
// k floats per lane = 2 float4 at immediate offsets; each frag-pair consumes
// exactly one 128B line) and converted in-register -> B never touches LDS.
// A (x, bf16, L2-resident) lives in LDS: [128 rows][128 k] panel, double-
// buffered (64KB total), wave-tile 128x64 (1x4 wave grid) so each wave reads
// the A panel once. One barrier per panel (2 K64-steps); counted vmcnt(8)
// keeps the next B frag-group in flight across it.
// LDS swizzle: 16B chunk g of row r holds source chunk (g&8)|((g&7)^(r&7)).
__global__ __launch_bounds__(256, 2) void k_gemm(
    const float* __restrict__ W,            // [VOCAB][DIM] fp32
    const unsigned short* __restrict__ Xb,  // [MPAD][DIM] bf16
    float* __restrict__ S)                  // [MPAD] running sum of exp(z-30)
{
  __shared__ unsigned short As[2 * PANE];   // 64 KB

  // ---- bijective XCD swizzle (m204), rb-fastest logical order ----
  const int q  = NWG / 8, rm = NWG % 8;     // 640, 5
  const int orig = blockIdx.x;
  const int xcd  = orig & 7;
  const int part = orig >> 3;
  const int bid  = (xcd < rm ? xcd * (q + 1) : rm * (q + 1) + (xcd - rm) * q) + part;

  const int rb  = bid % RB;
  const int vb  = bid / RB;
  const int m0  = rb * BM;
  const long n0 = (long)vb * BN;

  const int t   = threadIdx.x;
  const int l   = t & 63;
  const int w   = t >> 6;                   // wave 0..3 -> vocab band
  const int l15 = l & 15, lh = l >> 4;      // lh in 0..3
  const int e8  = l15 & 7;

  // A-frag vaddr (elements) per kk: row part + swizzled chunk part
  const int va0 = l15 * 128 + ((lh      ) ^ e8) * 8;   // kk=0
  const int va1 = l15 * 128 + ((4 + lh  ) ^ e8) * 8;   // kk=1

  // B per-lane row-base pointers (include lh*8 so loads are base + kidx*128B)
  const float* bbase0 = W + (size_t)(n0 + w * 64 +  0 + l15) * DIM + lh * 8;
  const float* bbase1 = W + (size_t)(n0 + w * 64 + 16 + l15) * DIM + lh * 8;
  const float* bbase2 = W + (size_t)(n0 + w * 64 + 32 + l15) * DIM + lh * 8;
  const float* bbase3 = W + (size_t)(n0 + w * 64 + 48 + l15) * DIM + lh * 8;

  // A staging: thread's source chunk swizzle is CONSTANT across i:
  // r = (t>>4) + 16*i  ->  r&7 == (t>>4)&7;  g = t&15.
  const int sg  = t & 15;
  const int sc  = (sg & 8) | ((sg & 7) ^ ((t >> 4) & 7));  // source chunk
  const unsigned short* agbase = Xb + (size_t)(m0 + (t >> 4)) * DIM + sc * 8;

  f32x4 acc[8][4];
  const f32x4 zero4 = {0.0f, 0.0f, 0.0f, 0.0f};
  #pragma unroll
  for (int i = 0; i < 8; ++i)
    #pragma unroll
    for (int j = 0; j < 4; ++j) acc[i][j] = zero4;

  float4 fbA[4][2], fbB[4][2];              // named B reg dbuf (rule #20)

#define ISSUE_A(NB, NS)                                                        \
  _Pragma("unroll")                                                            \
  for (int i = 0; i < 8; ++i) {                                                \
    const unsigned short* gp = agbase + (NS) * 128 + (size_t)i * (16 * DIM);   \
    __builtin_amdgcn_global_load_lds((const AS1 void*)gp,                      \
        (AS3 void*)(As + (NB) * PANE + t * 8 + i * 2048), 16, 0, 0);           \
  }

#define ISSUE_B(FB, KIDX)                                                      \
  {                                                                            \
    FB[0][0] = *(const float4*)(bbase0 + (KIDX) * 32);                         \
    FB[0][1] = *(const float4*)(bbase0 + (KIDX) * 32 + 4);                     \
    FB[1][0] = *(const float4*)(bbase1 + (KIDX) * 32);                         \
    FB[1][1] = *(const float4*)(bbase1 + (KIDX) * 32 + 4);                     \
    FB[2][0] = *(const float4*)(bbase2 + (KIDX) * 32);                         \
    FB[2][1] = *(const float4*)(bbase2 + (KIDX) * 32 + 4);                     \
    FB[3][0] = *(const float4*)(bbase3 + (KIDX) * 32);                         \
    FB[3][1] = *(const float4*)(bbase3 + (KIDX) * 32 + 4);                     \
  }

#define SUB(PB, KS, VA, CUR, NXT, NKIDX)                                       \
  {                                                                            \
    ISSUE_B(NXT, NKIDX)                                                        \
    union { u16x8 v; bf16x8 b; } bb[4];                                        \
    _Pragma("unroll")                                                          \
    for (int ni = 0; ni < 4; ++ni) {                                           \
      bb[ni].v[0] = (u16x8){0,0,0,0,0,0,0,0}[0]; /* no-op init */              \
      unsigned u0 = cvt_pk_bf16(CUR[ni][0].x, CUR[ni][0].y);                   \
      unsigned u1 = cvt_pk_bf16(CUR[ni][0].z, CUR[ni][0].w);                   \
      unsigned u2 = cvt_pk_bf16(CUR[ni][1].x, CUR[ni][1].y);                   \
      unsigned u3 = cvt_pk_bf16(CUR[ni][1].z, CUR[ni][1].w);                   \
      union { unsigned uu[4]; u16x8 vv; } m_;                                  \
      m_.uu[0] = u0; m_.uu[1] = u1; m_.uu[2] = u2; m_.uu[3] = u3;              \
      bb[ni].v = m_.vv;                                                        \
    }                                                                          \
    __builtin_amdgcn_s_setprio(1);                                             \
    _Pragma("unroll")                                                          \
    for (int mi = 0; mi < 8; ++mi) {                                           \
      bf16x8 af = *(const bf16x8*)(As + (PB) * PANE + mi * 2048                \
                                      + (KS) * 64 + (VA));                     \
      _Pragma("unroll")                                                        \
      for (int ni = 0; ni < 4; ++ni)                                           \
        acc[mi][ni] = __builtin_amdgcn_mfma_f32_16x16x32_bf16(                 \
            af, bb[ni].b, acc[mi][ni], 0, 0, 0);                               \
    }                                                                          \
    __builtin_amdgcn_s_setprio(0);                                             \
  }

#define PERIOD(P)                                                              \
  {                                                                            \
    ISSUE_A(((P) + 1) & 1, ((P) + 1) & 7)                                      \
    __builtin_amdgcn_sched_barrier(0);                                         \
    SUB((P) & 1, 0, va0, fbA, fbB, ((P) * 4 + 1) & 31)                         \
    SUB((P) & 1, 0, va1, fbB, fbA, ((P) * 4 + 2) & 31)                         \
    SUB((P) & 1, 1, va0, fbA, fbB, ((P) * 4 + 3) & 31)                         \
    SUB((P) & 1, 1, va1, fbB, fbA, ((P) * 4 + 4) & 31)                         \
    asm volatile("s_waitcnt vmcnt(8)" ::: "memory");                           \
    __builtin_amdgcn_sched_barrier(0);                                         \
    __builtin_amdgcn_s_barrier();                                              \
  }

  // ---- prologue: stage panel 0 -> buf0; B kidx 0 -> fbA ----
  ISSUE_A(0, 0)
  __builtin_amdgcn_sched_barrier(0);
  ISSUE_B(fbA, 0)
  asm volatile("s_waitcnt vmcnt(8)" ::: "memory");   // A landed; B in flight
  __builtin_amdgcn_sched_barrier(0);
  __builtin_amdgcn_s_barrier();

  PERIOD(0) PERIOD(1) PERIOD(2) PERIOD(3)
  PERIOD(4) PERIOD(5) PERIOD(6) PERIOD(7)

  // ---- epilogue: p = exp(z-30) = exp(-60/(exp(g/15)+1)), row sums, atomics
  // C frag layout: col = l&15 (vocab, this wave's 64-band), row = lh*4+j
  #pragma unroll
  for (int mi = 0; mi < 8; ++mi) {
    #pragma unroll
    for (int j = 0; j < 4; ++j) {
      float s = 0.0f;
      #pragma unroll
      for (int ni = 0; ni < 4; ++ni) {
        float g   = acc[mi][ni][j];
        float tp1 = __expf(g * (1.0f / 15.0f)) + 1.0f;
        s += __expf(-60.0f * __builtin_amdgcn_rcpf(tp1));
      }
      s += __shfl_xor(s, 1);
      s += __shfl_xor(s, 2);
      s += __shfl_xor(s, 4);
      s += __shfl_xor(s, 8);
      if (l15 == 0) {
        int row = m0 + mi * 16 + lh * 4 + j;
        atomicAdd(&S[row], s);              // padded rows land in S[576..640)
      }
    }
  }
#undef ISSUE_A
#undef ISSUE_B
#undef SUB
#undef PERIOD
}

// ---------- kernel 3: exact fp32 target logits ----------
__global__ void k_tgt(const float* __restrict__ x, const float* __restrict__ W,
                      const int* __restrict__ labels, float* __restrict__ tgt) {
  int n = blockIdx.x;
  int lab = labels[n];
  int t = threadIdx.x;                       // 256 threads * 4 floats = 1024
  float s = 0.0f;
  if (lab >= 0) {
    const float4 a = ((const float4*)(x + (size_t)n * DIM))[t];
    const float4 b = ((const float4*)(W + (size_t)lab * DIM))[t];
    s = a.x*b.x + a.y*b.y + a.z*b.z + a.w*b.w;
  }
  #pragma unroll
  for (int off = 32; off >= 1; off >>= 1) s += __shfl_xor(s, off);
  __shared__ float wsum[4];
  if ((t & 63) == 0) wsum[t >> 6] = s;
  __syncthreads();
  if (t == 0) {
    float d = wsum[0] + wsum[1] + wsum[2] + wsum[3];
    tgt[n] = (lab >= 0) ? 30.0f * tanhf(d * (1.0f / 30.0f)) : 0.0f;
  }
}

// ---------- kernel 4: final reduce -> loss ----------
__global__ void k_final(const float* __restrict__ S, const float* __restrict__ tgt,
                        const int* __restrict__ labels, float* __restrict__ out) {
  int t = threadIdx.x;
  float sum = 0.0f, cnt = 0.0f;
  for (int n = t; n < N_TOK; n += 256) {
    if (labels[n] != IGNORE_INDEX) {
      sum += 30.0f + __logf(S[n]) - tgt[n];  // lse = 30 + log(sum exp(z-30))
      cnt += 1.0f;
    }
  }
  #pragma unroll
  for (int off = 32; off >= 1; off >>= 1) {
    sum += __shfl_xor(sum, off);
    cnt += __shfl_xor(cnt, off);
  }
  __shared__ float as_[4], ac_[4];
  if ((t & 63) == 0) { as_[t >> 6] = sum; ac_[t >> 6] = cnt; }
  __syncthreads();
  if (t == 0) {
    float ts = as_[0] + as_[1] + as_[2] + as_[3];
    float tc = ac_[0] + ac_[1] + ac_[2] + ac_[3];
    out[0] = ts / tc;
  }
}

extern "C" void kernel_launch(void* const* d_in, const int* in_sizes, int n_in,
                              void* d_out, int out_size, void* d_ws, size_t ws_size,
                              hipStream_t stream) {
  const float* x      = (const float*)d_in[0];
  const float* W      = (const float*)d_in[1];
  const int*   labels = (const int*)d_in[2];
  float* out = (float*)d_out;

  // ws layout: xb [640*1024 bf16] | S [640 f32] | tgt [576 f32]  (~1.26 MB)
  char* ws = (char*)d_ws;
  unsigned short* xb = (unsigned short*)ws;
  float* S   = (float*)(ws + (size_t)MPAD * DIM * 2);
  float* tgt = (float*)(ws + (size_t)MPAD * DIM * 2 + MPAD * 4);

  hipMemsetAsync(S, 0, MPAD * sizeof(float), stream);   // zero accumulators
  k_cvt_x<<<MPAD * DIM / (256 * 8), 256, 0, stream>>>(x, xb);
  k_gemm<<<NWG, 256, 0, stream>>>(W, xb, S);
  k_tgt<<<N_TOK, 256, 0, stream>>>(x, W, labels, tgt);
  k_final<<<1, 256, 0, stream>>>(S, tgt, labels, out);
}